// Round 4
// baseline (182.951 us; speedup 1.0000x reference)
//
#include <hip/hip_runtime.h>
#include <math.h>

// Problem constants: bases [1,4,136,200] f32, box_feat [N,789] f32
// (col0 = image idx, 1:5 = box, 5: = 4*14*14 coeffs), out [N,544,800] f32.
#define OUTD 56
#define COD  14
#define BH   136
#define BW   200
#define IMGH 544
#define IMGW 800
#define BB   4
#define BFS  789   // 5 + 4*14*14

// ---------------------------------------------------------------------------
// K1: build N 56x56 sigmoid masks into workspace. One thread per pixel
// (grid = 13 x N) -> full chip, one heavy eval per thread.
// ---------------------------------------------------------------------------
__global__ __launch_bounds__(256) void mask_kernel(
    const float* __restrict__ bases,
    const float* __restrict__ box_feat,
    float* __restrict__ masks) {
  const int n = blockIdx.y;
  const int p = blockIdx.x * 256 + threadIdx.x;
  if (p >= OUTD * OUTD) return;
  const int y = p / OUTD;
  const int x = p - y * OUTD;

  const float* bf = box_feat + (size_t)n * BFS;
  const int bidx = (int)bf[0];
  const float x0 = bf[1], y0 = bf[2], x1 = bf[3], y1 = bf[4];
  const float sx0 = x0 * 0.25f - 0.5f;
  const float sy0 = y0 * 0.25f - 0.5f;
  const float bwv = (x1 - x0) * 0.25f * (1.0f / OUTD);
  const float bhv = (y1 - y0) * 0.25f * (1.0f / OUTD);
  const float* feat = bases + (size_t)bidx * BB * BH * BW;
  const float* top  = bf + 5;

  // ---- roi_align sample (aligned=True, sampling_ratio=1) ----
  const float ysv = sy0 + ((float)y + 0.5f) * bhv;
  const float xsv = sx0 + ((float)x + 0.5f) * bwv;
  const float valid =
      (ysv >= -1.0f && ysv <= (float)BH && xsv >= -1.0f && xsv <= (float)BW)
          ? 1.0f : 0.0f;
  const float yc = fminf(fmaxf(ysv, 0.0f), (float)(BH - 1));
  const float xc = fminf(fmaxf(xsv, 0.0f), (float)(BW - 1));
  int yl = (int)floorf(yc); yl = yl > (BH - 2) ? (BH - 2) : yl;  // yc >= 0
  int xl = (int)floorf(xc); xl = xl > (BW - 2) ? (BW - 2) : xl;
  const float ly = yc - (float)yl, hy = 1.0f - ly;
  const float lx = xc - (float)xl, hx = 1.0f - lx;
  const float w00 = hy * hx, w01 = hy * lx, w10 = ly * hx, w11 = ly * lx;

  // ---- coeff 14->56 bilinear upsample coords (edge clamp) ----
  float cyf = fminf(fmaxf(((float)y + 0.5f) * 0.25f - 0.5f, 0.0f), (float)(COD - 1));
  float cxf = fminf(fmaxf(((float)x + 0.5f) * 0.25f - 0.5f, 0.0f), (float)(COD - 1));
  int cyl = (int)floorf(cyf); cyl = cyl > (COD - 2) ? (COD - 2) : cyl;
  int cxl = (int)floorf(cxf); cxl = cxl > (COD - 2) ? (COD - 2) : cxl;
  const float cly = cyf - (float)cyl, chy = 1.0f - cly;
  const float clx = cxf - (float)cxl, chx = 1.0f - clx;
  const float cw00 = chy * chx, cw01 = chy * clx, cw10 = cly * chx, cw11 = cly * clx;

  float rvals[BB], cvals[BB];
#pragma unroll
  for (int b = 0; b < BB; ++b) {
    const float* fb = feat + b * BH * BW;
    const float r = w00 * fb[yl * BW + xl]       + w01 * fb[yl * BW + xl + 1] +
                    w10 * fb[(yl + 1) * BW + xl] + w11 * fb[(yl + 1) * BW + xl + 1];
    rvals[b] = r * valid;
    const float* tb = top + b * COD * COD;
    cvals[b] = cw00 * tb[cyl * COD + cxl]       + cw01 * tb[cyl * COD + cxl + 1] +
               cw10 * tb[(cyl + 1) * COD + cxl] + cw11 * tb[(cyl + 1) * COD + cxl + 1];
  }

  const float mx = fmaxf(fmaxf(cvals[0], cvals[1]), fmaxf(cvals[2], cvals[3]));
  float e[BB], s = 0.0f;
#pragma unroll
  for (int b = 0; b < BB; ++b) { e[b] = __expf(cvals[b] - mx); s += e[b]; }
  const float inv = 1.0f / s;
  float dot = 0.0f;
#pragma unroll
  for (int b = 0; b < BB; ++b) dot += rvals[b] * (e[b] * inv);
  masks[(size_t)n * (OUTD * OUTD) + p] = 1.0f / (1.0f + __expf(-dot));
}

// ---------------------------------------------------------------------------
// K2: interior-only paste. d_out is pre-zeroed by hipMemsetAsync (fill kernel
// runs at 6.5 TB/s — measured); this kernel only touches rows/cols inside the
// box's conservative tent support (~5% of pixels). One block per
// (candidate-row, roi); stages the 2 needed mask rows into LDS; threads cover
// the box's column window in <=2 coalesced chunks of 256 scalar stores.
// ---------------------------------------------------------------------------
// Max vertical support: box height <= 217.6 px, tent slack <= ~2.5 rows each
// side -> 226 candidate rows is conservative.
#define MAXROWS 226

__global__ __launch_bounds__(256) void paste_interior(
    const float* __restrict__ masks,
    const float* __restrict__ box_feat,
    float* __restrict__ out) {
  const int n = blockIdx.y;
  const int tid = threadIdx.x;

  const float* bf = box_feat + (size_t)n * BFS;
  const float x0 = bf[1], y0 = bf[2], x1 = bf[3], y1 = bf[4];

  const int hs = max(0, (int)floorf(y0) - 3);
  const int h  = hs + (int)blockIdx.x;
  if (h >= IMGH) return;

  const float fy = ((float)h + 0.5f - y0) * ((float)OUTD / (y1 - y0)) - 0.5f;
  if (!(fy > -1.0f && fy < (float)OUTD)) return;   // block-uniform

  const int ml = (int)floorf(fy);                  // -1 .. 55
  const float wy1 = fy - (float)ml;
  const float wy0 = 1.0f - wy1;

  __shared__ float mrow[2][OUTD];
  if (tid < 2 * OUTD) {
    const int r_idx = (tid >= OUTD) ? 1 : 0;
    const int x = tid - r_idx * OUTD;
    const int r = ml + r_idx;
    float v = 0.0f;
    if (r >= 0 && r < OUTD)
      v = masks[(size_t)n * (OUTD * OUTD) + r * OUTD + x];
    mrow[r_idx][x] = v;                            // 0 => zero-pad semantics
  }
  __syncthreads();

  // Conservative column window of the tent support.
  const int qs = max(0, (int)floorf(x0) - 4);
  const int qe = min(IMGW - 1, (int)ceilf(x1) + 3);

  const float invw = (float)OUTD / (x1 - x0);
  const float cxc = (0.5f - x0) * invw - 0.5f;     // fx(q) = q*invw + cxc

  float* orow = out + ((size_t)n * IMGH + h) * IMGW;
  for (int q = qs + tid; q <= qe; q += 256) {
    const float fx = fmaf((float)q, invw, cxc);
    float v = 0.0f;
    if (fx > -1.0f && fx < (float)OUTD) {
      const int xl = (int)floorf(fx);
      float wx1 = fx - (float)xl;
      float wx0 = 1.0f - wx1;
      const int xls = xl < 0 ? 0 : xl;
      const int xhs = (xl + 1 > OUTD - 1) ? (OUTD - 1) : (xl + 1);
      if (xl < 0) wx0 = 0.0f;
      if (xl + 1 > OUTD - 1) wx1 = 0.0f;
      v = wy0 * (wx0 * mrow[0][xls] + wx1 * mrow[0][xhs]) +
          wy1 * (wx0 * mrow[1][xls] + wx1 * mrow[1][xhs]);
    }
    orow[q] = v;   // writing 0 outside tent-but-inside-window is harmless
  }
}

extern "C" void kernel_launch(void* const* d_in, const int* in_sizes, int n_in,
                              void* d_out, int out_size, void* d_ws, size_t ws_size,
                              hipStream_t stream) {
  const float* bases    = (const float*)d_in[0];
  const float* box_feat = (const float*)d_in[1];
  const int N = in_sizes[1] / BFS;

  float* masks = (float*)d_ws;  // N*56*56 floats = 1.25 MB for N=100

  // Zero the full output at fill-kernel speed (6.5 TB/s measured).
  hipMemsetAsync(d_out, 0, (size_t)out_size * sizeof(float), stream);

  dim3 g1((OUTD * OUTD + 255) / 256, N);
  mask_kernel<<<g1, 256, 0, stream>>>(bases, box_feat, masks);

  dim3 g2(MAXROWS, N);
  paste_interior<<<g2, 256, 0, stream>>>(masks, box_feat, (float*)d_out);
}

// Round 5
// 180.033 us; speedup vs baseline: 1.0162x; 1.0162x over previous
//
#include <hip/hip_runtime.h>
#include <math.h>

// Problem constants: bases [1,4,136,200] f32, box_feat [N,789] f32
// (col0 = image idx, 1:5 = box, 5: = 4*14*14 coeffs), out [N,544,800] f32.
#define OUTD 56
#define COD  14
#define BH   136
#define BW   200
#define IMGH 544
#define IMGW 800
#define BB   4
#define BFS  789    // 5 + 4*14*14
#define GRP  8      // image rows per paste block; IMGH/GRP = 68
#define W4   (IMGW / 4)          // 200 float4 per row
#define ELEMS (GRP * W4)         // 1600 float4 per block

// ---------------------------------------------------------------------------
// K1: build N 56x56 sigmoid masks into workspace. One thread per pixel
// (grid = 13 x N).
// ---------------------------------------------------------------------------
__global__ __launch_bounds__(256) void mask_kernel(
    const float* __restrict__ bases,
    const float* __restrict__ box_feat,
    float* __restrict__ masks) {
  const int n = blockIdx.y;
  const int p = blockIdx.x * 256 + threadIdx.x;
  if (p >= OUTD * OUTD) return;
  const int y = p / OUTD;
  const int x = p - y * OUTD;

  const float* bf = box_feat + (size_t)n * BFS;
  const int bidx = (int)bf[0];
  const float x0 = bf[1], y0 = bf[2], x1 = bf[3], y1 = bf[4];
  const float sx0 = x0 * 0.25f - 0.5f;
  const float sy0 = y0 * 0.25f - 0.5f;
  const float bwv = (x1 - x0) * 0.25f * (1.0f / OUTD);
  const float bhv = (y1 - y0) * 0.25f * (1.0f / OUTD);
  const float* feat = bases + (size_t)bidx * BB * BH * BW;
  const float* top  = bf + 5;

  // ---- roi_align sample (aligned=True, sampling_ratio=1) ----
  const float ysv = sy0 + ((float)y + 0.5f) * bhv;
  const float xsv = sx0 + ((float)x + 0.5f) * bwv;
  const float valid =
      (ysv >= -1.0f && ysv <= (float)BH && xsv >= -1.0f && xsv <= (float)BW)
          ? 1.0f : 0.0f;
  const float yc = fminf(fmaxf(ysv, 0.0f), (float)(BH - 1));
  const float xc = fminf(fmaxf(xsv, 0.0f), (float)(BW - 1));
  int yl = (int)floorf(yc); yl = yl > (BH - 2) ? (BH - 2) : yl;  // yc >= 0
  int xl = (int)floorf(xc); xl = xl > (BW - 2) ? (BW - 2) : xl;
  const float ly = yc - (float)yl, hy = 1.0f - ly;
  const float lx = xc - (float)xl, hx = 1.0f - lx;
  const float w00 = hy * hx, w01 = hy * lx, w10 = ly * hx, w11 = ly * lx;

  // ---- coeff 14->56 bilinear upsample coords (edge clamp) ----
  float cyf = fminf(fmaxf(((float)y + 0.5f) * 0.25f - 0.5f, 0.0f), (float)(COD - 1));
  float cxf = fminf(fmaxf(((float)x + 0.5f) * 0.25f - 0.5f, 0.0f), (float)(COD - 1));
  int cyl = (int)floorf(cyf); cyl = cyl > (COD - 2) ? (COD - 2) : cyl;
  int cxl = (int)floorf(cxf); cxl = cxl > (COD - 2) ? (COD - 2) : cxl;
  const float cly = cyf - (float)cyl, chy = 1.0f - cly;
  const float clx = cxf - (float)cxl, chx = 1.0f - clx;
  const float cw00 = chy * chx, cw01 = chy * clx, cw10 = cly * chx, cw11 = cly * clx;

  float rvals[BB], cvals[BB];
#pragma unroll
  for (int b = 0; b < BB; ++b) {
    const float* fb = feat + b * BH * BW;
    const float r = w00 * fb[yl * BW + xl]       + w01 * fb[yl * BW + xl + 1] +
                    w10 * fb[(yl + 1) * BW + xl] + w11 * fb[(yl + 1) * BW + xl + 1];
    rvals[b] = r * valid;
    const float* tb = top + b * COD * COD;
    cvals[b] = cw00 * tb[cyl * COD + cxl]       + cw01 * tb[cyl * COD + cxl + 1] +
               cw10 * tb[(cyl + 1) * COD + cxl] + cw11 * tb[(cyl + 1) * COD + cxl + 1];
  }

  const float mx = fmaxf(fmaxf(cvals[0], cvals[1]), fmaxf(cvals[2], cvals[3]));
  float e[BB], s = 0.0f;
#pragma unroll
  for (int b = 0; b < BB; ++b) { e[b] = __expf(cvals[b] - mx); s += e[b]; }
  const float inv = 1.0f / s;
  float dot = 0.0f;
#pragma unroll
  for (int b = 0; b < BB; ++b) dot += rvals[b] * (e[b] * inv);
  masks[(size_t)n * (OUTD * OUTD) + p] = 1.0f / (1.0f + __expf(-dot));
}

// ---------------------------------------------------------------------------
// K2: paste, 8 rows per block (grid = 68 x N). All-zero groups take a pure
// store loop (fill-kernel structure: 6.25 float4/thread, all 256 threads
// active). Interior groups stage the whole 12.5 KB mask into LDS once, then
// each thread handles 6.25 flattened (row, col4) elements with predicated
// bilinear sampling. No memset, no per-row barriers, no idle store lanes.
// ---------------------------------------------------------------------------
__global__ __launch_bounds__(256) void paste_group(
    const float* __restrict__ masks,
    const float* __restrict__ box_feat,
    float4* __restrict__ out) {
  const int n  = blockIdx.y;
  const int hs = (int)blockIdx.x * GRP;
  const int tid = threadIdx.x;

  const float* bf = box_feat + (size_t)n * BFS;
  const float x0 = bf[1], y0 = bf[2], x1 = bf[3], y1 = bf[4];

  float4* obase = out + ((size_t)n * IMGH + hs) * W4;

  const float sy = (float)OUTD / (y1 - y0);
  const float cyc_ = (0.5f - y0) * sy - 0.5f;      // fy(h) = h*sy + cyc_
  const float fy_first = (float)hs * sy + cyc_;
  const float fy_last  = (float)(hs + GRP - 1) * sy + cyc_;

  // Group entirely outside vertical tent support -> pure zero-store loop.
  if (!(fy_last > -1.0f && fy_first < (float)OUTD)) {
    const float4 z = make_float4(0.f, 0.f, 0.f, 0.f);
    for (int idx = tid; idx < ELEMS; idx += 256) obase[idx] = z;
    return;
  }

  // Stage the whole mask for this roi into LDS (12.5 KB).
  __shared__ float m[OUTD * OUTD];
  {
    const float* msrc = masks + (size_t)n * (OUTD * OUTD);
    for (int i = tid; i < OUTD * OUTD; i += 256) m[i] = msrc[i];
  }
  __syncthreads();

  const float invw = (float)OUTD / (x1 - x0);
  const float cxc = (0.5f - x0) * invw - 0.5f;     // fx(q) = q*invw + cxc

  // Flattened loop over GRP*W4 elements; step 256 = 1*W4 + 56.
  int row = tid / W4;
  int col = tid - row * W4;
  for (int idx = tid; idx < ELEMS; idx += 256) {
    const float fy = (float)(hs + row) * sy + cyc_;
    float4 o = make_float4(0.f, 0.f, 0.f, 0.f);
    if (fy > -1.0f && fy < (float)OUTD) {
      const int ml = (int)floorf(fy);              // -1 .. 55
      float wy1 = fy - (float)ml;
      float wy0 = 1.0f - wy1;
      const int r0 = ml < 0 ? 0 : ml;
      const int r1 = (ml + 1 > OUTD - 1) ? (OUTD - 1) : (ml + 1);
      if (ml < 0) wy0 = 0.0f;
      if (ml + 1 > OUTD - 1) wy1 = 0.0f;
      const float* row0 = &m[r0 * OUTD];
      const float* row1 = &m[r1 * OUTD];
      float res[4];
#pragma unroll
      for (int i = 0; i < 4; ++i) {
        const float q = (float)(col * 4 + i);
        const float fx = fmaf(q, invw, cxc);
        float v = 0.0f;
        if (fx > -1.0f && fx < (float)OUTD) {
          const int xl = (int)floorf(fx);
          float wx1 = fx - (float)xl;
          float wx0 = 1.0f - wx1;
          const int xls = xl < 0 ? 0 : xl;
          const int xhs = (xl + 1 > OUTD - 1) ? (OUTD - 1) : (xl + 1);
          if (xl < 0) wx0 = 0.0f;
          if (xl + 1 > OUTD - 1) wx1 = 0.0f;
          v = wy0 * (wx0 * row0[xls] + wx1 * row0[xhs]) +
              wy1 * (wx0 * row1[xls] + wx1 * row1[xhs]);
        }
        res[i] = v;
      }
      o = make_float4(res[0], res[1], res[2], res[3]);
    }
    obase[row * W4 + col] = o;
    // advance flat index by 256 = W4 + 56
    row += 1;
    col += 56;
    if (col >= W4) { col -= W4; row += 1; }
  }
}

extern "C" void kernel_launch(void* const* d_in, const int* in_sizes, int n_in,
                              void* d_out, int out_size, void* d_ws, size_t ws_size,
                              hipStream_t stream) {
  const float* bases    = (const float*)d_in[0];
  const float* box_feat = (const float*)d_in[1];
  const int N = in_sizes[1] / BFS;

  float* masks = (float*)d_ws;  // N*56*56 floats = 1.25 MB for N=100

  dim3 g1((OUTD * OUTD + 255) / 256, N);
  mask_kernel<<<g1, 256, 0, stream>>>(bases, box_feat, masks);

  dim3 g2(IMGH / GRP, N);
  paste_group<<<g2, 256, 0, stream>>>(masks, box_feat, (float4*)d_out);
}

// Round 6
// 175.014 us; speedup vs baseline: 1.0453x; 1.0287x over previous
//
#include <hip/hip_runtime.h>
#include <math.h>

// Problem constants: bases [1,4,136,200] f32, box_feat [N,789] f32
// (col0 = image idx, 1:5 = box, 5: = 4*14*14 coeffs), out [N,544,800] f32.
#define OUTD 56
#define COD  14
#define BH   136
#define BW   200
#define IMGH 544
#define IMGW 800
#define BB   4
#define BFS  789    // 5 + 4*14*14
#define GRP  8      // image rows per block; IMGH/GRP = 68
#define W4   (IMGW / 4)          // 200 float4 per row
#define ELEMS (GRP * W4)         // 1600 float4 per block

// ---------------------------------------------------------------------------
// Heavy mask eval at mask pixel (y, x) for one roi:
// roi_align(bases, aligned=True, sampling_ratio=1) + 14->56 bilinear coeff
// upsample + softmax over 4 bases + dot + sigmoid.
// ---------------------------------------------------------------------------
__device__ __forceinline__ float mask_value(
    const float* __restrict__ feat, const float* __restrict__ top,
    float sx0, float sy0, float bwv, float bhv, int y, int x) {
  const float ysv = sy0 + ((float)y + 0.5f) * bhv;
  const float xsv = sx0 + ((float)x + 0.5f) * bwv;
  const float valid =
      (ysv >= -1.0f && ysv <= (float)BH && xsv >= -1.0f && xsv <= (float)BW)
          ? 1.0f : 0.0f;
  const float yc = fminf(fmaxf(ysv, 0.0f), (float)(BH - 1));
  const float xc = fminf(fmaxf(xsv, 0.0f), (float)(BW - 1));
  int yl = (int)floorf(yc); yl = yl > (BH - 2) ? (BH - 2) : yl;  // yc >= 0
  int xl = (int)floorf(xc); xl = xl > (BW - 2) ? (BW - 2) : xl;
  const float ly = yc - (float)yl, hy = 1.0f - ly;
  const float lx = xc - (float)xl, hx = 1.0f - lx;
  const float w00 = hy * hx, w01 = hy * lx, w10 = ly * hx, w11 = ly * lx;

  float cyf = fminf(fmaxf(((float)y + 0.5f) * 0.25f - 0.5f, 0.0f), (float)(COD - 1));
  float cxf = fminf(fmaxf(((float)x + 0.5f) * 0.25f - 0.5f, 0.0f), (float)(COD - 1));
  int cyl = (int)floorf(cyf); cyl = cyl > (COD - 2) ? (COD - 2) : cyl;
  int cxl = (int)floorf(cxf); cxl = cxl > (COD - 2) ? (COD - 2) : cxl;
  const float cly = cyf - (float)cyl, chy = 1.0f - cly;
  const float clx = cxf - (float)cxl, chx = 1.0f - clx;
  const float cw00 = chy * chx, cw01 = chy * clx, cw10 = cly * chx, cw11 = cly * clx;

  float rvals[BB], cvals[BB];
#pragma unroll
  for (int b = 0; b < BB; ++b) {
    const float* fb = feat + b * BH * BW;
    const float r = w00 * fb[yl * BW + xl]       + w01 * fb[yl * BW + xl + 1] +
                    w10 * fb[(yl + 1) * BW + xl] + w11 * fb[(yl + 1) * BW + xl + 1];
    rvals[b] = r * valid;
    const float* tb = top + b * COD * COD;
    cvals[b] = cw00 * tb[cyl * COD + cxl]       + cw01 * tb[cyl * COD + cxl + 1] +
               cw10 * tb[(cyl + 1) * COD + cxl] + cw11 * tb[(cyl + 1) * COD + cxl + 1];
  }

  const float mx = fmaxf(fmaxf(cvals[0], cvals[1]), fmaxf(cvals[2], cvals[3]));
  float e[BB], s = 0.0f;
#pragma unroll
  for (int b = 0; b < BB; ++b) { e[b] = __expf(cvals[b] - mx); s += e[b]; }
  const float inv = 1.0f / s;
  float dot = 0.0f;
#pragma unroll
  for (int b = 0; b < BB; ++b) dot += rvals[b] * (e[b] * inv);
  return 1.0f / (1.0f + __expf(-dot));
}

// ---------------------------------------------------------------------------
// Single fused kernel: 8 output rows per block (grid = 68 x N).
// Zero groups: pure float4 zero-store loop (fill-kernel structure).
// Interior groups: compute ONLY the mask rows this group needs (~10-16 of 56,
// ~3 heavy evals/thread) into LDS, then flattened predicated bilinear paste —
// all 256 threads store 6.25 float4 each, coalesced. One dispatch total:
// no mask pre-pass, no workspace, no inter-kernel gap.
// ---------------------------------------------------------------------------
__global__ __launch_bounds__(256) void fused_paste(
    const float* __restrict__ bases,
    const float* __restrict__ box_feat,
    float4* __restrict__ out) {
  const int n  = blockIdx.y;
  const int hs = (int)blockIdx.x * GRP;
  const int tid = threadIdx.x;

  const float* bf = box_feat + (size_t)n * BFS;
  const float x0 = bf[1], y0 = bf[2], x1 = bf[3], y1 = bf[4];

  float4* obase = out + ((size_t)n * IMGH + hs) * W4;

  const float sy = (float)OUTD / (y1 - y0);
  const float cyc_ = (0.5f - y0) * sy - 0.5f;      // fy(h) = h*sy + cyc_
  const float fy_first = (float)hs * sy + cyc_;
  const float fy_last  = (float)(hs + GRP - 1) * sy + cyc_;

  // Group entirely outside vertical tent support -> pure zero-store loop.
  if (!(fy_last > -1.0f && fy_first < (float)OUTD)) {
    const float4 z = make_float4(0.f, 0.f, 0.f, 0.f);
    for (int idx = tid; idx < ELEMS; idx += 256) obase[idx] = z;
    return;
  }

  // ---- compute the needed mask rows into LDS ----
  // Rows read by this group: [floor(fy_first), floor(fy_last)+1] clamped to
  // [0,55]. All clamped read indices below land inside this range.
  __shared__ float m[OUTD * OUTD];
  {
    const int lo = max(0, (int)floorf(fy_first));
    const int hi = min(OUTD - 1, (int)floorf(fy_last) + 1);
    const int cnt = (hi - lo + 1) * OUTD;

    const int bidx = (int)bf[0];
    const float sx0 = x0 * 0.25f - 0.5f;
    const float sy0 = y0 * 0.25f - 0.5f;
    const float bwv = (x1 - x0) * 0.25f * (1.0f / OUTD);
    const float bhv = (y1 - y0) * 0.25f * (1.0f / OUTD);
    const float* feat = bases + (size_t)bidx * BB * BH * BW;
    const float* top  = bf + 5;

    for (int i = tid; i < cnt; i += 256) {
      const int r = lo + i / OUTD;
      const int x = i - (i / OUTD) * OUTD;
      m[r * OUTD + x] = mask_value(feat, top, sx0, sy0, bwv, bhv, r, x);
    }
  }
  __syncthreads();

  const float invw = (float)OUTD / (x1 - x0);
  const float cxc = (0.5f - x0) * invw - 0.5f;     // fx(q) = q*invw + cxc

  // Flattened loop over GRP*W4 elements; step 256 = 1*W4 + 56.
  int row = tid / W4;
  int col = tid - row * W4;
  for (int idx = tid; idx < ELEMS; idx += 256) {
    const float fy = (float)(hs + row) * sy + cyc_;
    float4 o = make_float4(0.f, 0.f, 0.f, 0.f);
    if (fy > -1.0f && fy < (float)OUTD) {
      const int ml = (int)floorf(fy);              // -1 .. 55
      float wy1 = fy - (float)ml;
      float wy0 = 1.0f - wy1;
      const int r0 = ml < 0 ? 0 : ml;
      const int r1 = (ml + 1 > OUTD - 1) ? (OUTD - 1) : (ml + 1);
      if (ml < 0) wy0 = 0.0f;
      if (ml + 1 > OUTD - 1) wy1 = 0.0f;
      const float* row0 = &m[r0 * OUTD];
      const float* row1 = &m[r1 * OUTD];
      float res[4];
#pragma unroll
      for (int i = 0; i < 4; ++i) {
        const float q = (float)(col * 4 + i);
        const float fx = fmaf(q, invw, cxc);
        float v = 0.0f;
        if (fx > -1.0f && fx < (float)OUTD) {
          const int xl = (int)floorf(fx);
          float wx1 = fx - (float)xl;
          float wx0 = 1.0f - wx1;
          const int xls = xl < 0 ? 0 : xl;
          const int xhs = (xl + 1 > OUTD - 1) ? (OUTD - 1) : (xl + 1);
          if (xl < 0) wx0 = 0.0f;
          if (xl + 1 > OUTD - 1) wx1 = 0.0f;
          v = wy0 * (wx0 * row0[xls] + wx1 * row0[xhs]) +
              wy1 * (wx0 * row1[xls] + wx1 * row1[xhs]);
        }
        res[i] = v;
      }
      o = make_float4(res[0], res[1], res[2], res[3]);
    }
    obase[row * W4 + col] = o;
    // advance flat index by 256 = W4 + 56
    row += 1;
    col += 56;
    if (col >= W4) { col -= W4; row += 1; }
  }
}

extern "C" void kernel_launch(void* const* d_in, const int* in_sizes, int n_in,
                              void* d_out, int out_size, void* d_ws, size_t ws_size,
                              hipStream_t stream) {
  const float* bases    = (const float*)d_in[0];
  const float* box_feat = (const float*)d_in[1];
  const int N = in_sizes[1] / BFS;

  dim3 grid(IMGH / GRP, N);
  fused_paste<<<grid, 256, 0, stream>>>(bases, box_feat, (float4*)d_out);
}